// Round 2
// baseline (229.287 us; speedup 1.0000x reference)
//
#include <hip/hip_runtime.h>
#include <math.h>

constexpr int KK = 2;
constexpr int HH = 4;
constexpr int NN = 4096;
constexpr int DD = 64;
constexpr int OO = 64;
constexpr int NU = 4000;
constexpr int CC = 2;
constexpr int JSPLIT = 8;
constexpr int JCHUNK = NN / JSPLIT;  // 512
constexpr float LOG2E = 1.44269504088896340736f;

typedef float vf4 __attribute__((ext_vector_type(4)));
typedef float vf2 __attribute__((ext_vector_type(2)));

__device__ __forceinline__ float fexp2(float x) {
#if __has_builtin(__builtin_amdgcn_exp2f)
  return __builtin_amdgcn_exp2f(x);
#else
  return exp2f(x);
#endif
}
__device__ __forceinline__ float frcp(float x) {
#if __has_builtin(__builtin_amdgcn_rcpf)
  return __builtin_amdgcn_rcpf(x);
#else
  return 1.0f / x;
#endif
}
__device__ __forceinline__ float ftanh(float x) {
  float e = fexp2(x * (2.0f * LOG2E));
  return 1.0f - 2.0f * frcp(e + 1.0f);
}

// ---------------------------------------------------------------------------
// Phase 1: per (k,h): hp = h @ w (4096x64 @ 64x64); per node n, PLANAR outputs:
//   Ap [kh][n] = 2^src'      A5p[kh][n] = 2^(0.2 src')   (src' = tanh-dot * log2e)
//   Bp [kh][n] = 2^dst'      B5p[kh][n] = 2^(0.2 dst')
//   G0p[kh][n] = hp_n.fc_w0  G1p[kh][n] = hp_n.fc_w1
// Factorized leaky-softmax: exp2(max(s,0.2s)) = max(A*B, A5*B5).
// grid (64, K*H), block 256. Thread = 4 rows x 4 o tile; LDS transpose epi.
// ---------------------------------------------------------------------------
__global__ __launch_bounds__(256) void gat_phase1(
    const float* __restrict__ hsrc, const float* __restrict__ w,
    const float* __restrict__ a_src, const float* __restrict__ a_dst,
    const float* __restrict__ fc_w,
    float* __restrict__ Ap, float* __restrict__ A5p,
    float* __restrict__ Bp, float* __restrict__ B5p,
    float* __restrict__ G0p, float* __restrict__ G1p) {
  const int kh = blockIdx.y;  // 0..7
  const int k = kh >> 2;
  const int i0 = blockIdx.x * 64;
  const int tid = threadIdx.x;

  __shared__ float h_s[DD][68];
  __shared__ float w_s[DD][OO];
  __shared__ float part[4][64][17];  // [val][row][og], padded

  {
    const vf4* wp = (const vf4*)(w + (size_t)kh * DD * OO);
    vf4* ws4 = (vf4*)w_s;
    for (int t = tid; t < DD * OO / 4; t += 256) ws4[t] = wp[t];
  }
  for (int t = tid; t < 1024; t += 256) {
    const int row = t >> 4;
    const int f4 = (t & 15) * 4;
    vf4 v = *(const vf4*)(hsrc + (size_t)(i0 + row) * DD + f4);
    h_s[f4 + 0][row] = v.x;
    h_s[f4 + 1][row] = v.y;
    h_s[f4 + 2][row] = v.z;
    h_s[f4 + 3][row] = v.w;
  }
  __syncthreads();

  const int og = tid & 15;
  const int rg = tid >> 4;
  const int o0 = og * 4;
  const int r0 = rg * 4;

  float hp[4][4];
#pragma unroll
  for (int j = 0; j < 4; ++j)
#pragma unroll
    for (int u = 0; u < 4; ++u) hp[j][u] = 0.0f;

#pragma unroll 8
  for (int f = 0; f < DD; ++f) {
    vf4 hv = *(const vf4*)&h_s[f][r0];
    vf4 wv = *(const vf4*)&w_s[f][o0];
    hp[0][0] = fmaf(hv.x, wv.x, hp[0][0]);
    hp[0][1] = fmaf(hv.x, wv.y, hp[0][1]);
    hp[0][2] = fmaf(hv.x, wv.z, hp[0][2]);
    hp[0][3] = fmaf(hv.x, wv.w, hp[0][3]);
    hp[1][0] = fmaf(hv.y, wv.x, hp[1][0]);
    hp[1][1] = fmaf(hv.y, wv.y, hp[1][1]);
    hp[1][2] = fmaf(hv.y, wv.z, hp[1][2]);
    hp[1][3] = fmaf(hv.y, wv.w, hp[1][3]);
    hp[2][0] = fmaf(hv.z, wv.x, hp[2][0]);
    hp[2][1] = fmaf(hv.z, wv.y, hp[2][1]);
    hp[2][2] = fmaf(hv.z, wv.z, hp[2][2]);
    hp[2][3] = fmaf(hv.z, wv.w, hp[2][3]);
    hp[3][0] = fmaf(hv.w, wv.x, hp[3][0]);
    hp[3][1] = fmaf(hv.w, wv.y, hp[3][1]);
    hp[3][2] = fmaf(hv.w, wv.z, hp[3][2]);
    hp[3][3] = fmaf(hv.w, wv.w, hp[3][3]);
  }

  float as[4], ad[4], f0[4], f1[4];
#pragma unroll
  for (int u = 0; u < 4; ++u) {
    as[u] = a_src[kh * OO + o0 + u];
    ad[u] = a_dst[kh * OO + o0 + u];
    f0[u] = fc_w[0 * (KK * OO) + k * OO + o0 + u];
    f1[u] = fc_w[1 * (KK * OO) + k * OO + o0 + u];
  }

#pragma unroll
  for (int j = 0; j < 4; ++j) {
    float sp = 0.0f, dp = 0.0f, g0 = 0.0f, g1 = 0.0f;
#pragma unroll
    for (int u = 0; u < 4; ++u) {
      float v = hp[j][u];
      float t = ftanh(v);
      sp = fmaf(t, as[u], sp);
      dp = fmaf(t, ad[u], dp);
      g0 = fmaf(v, f0[u], g0);
      g1 = fmaf(v, f1[u], g1);
    }
    part[0][r0 + j][og] = sp;
    part[1][r0 + j][og] = dp;
    part[2][r0 + j][og] = g0;
    part[3][r0 + j][og] = g1;
  }
  __syncthreads();

  {  // wave = val plane (uniform branch), lane = row j2; sum 16 og-partials
    const int val = tid >> 6;
    const int j2 = tid & 63;
    const float* pr = &part[val][j2][0];
    vf4 s0 = *(const vf4*)(pr + 0);
    vf4 s1 = *(const vf4*)(pr + 4);
    vf4 s2 = *(const vf4*)(pr + 8);
    vf4 s3 = *(const vf4*)(pr + 12);
    vf4 t4 = s0 + s1 + s2 + s3;
    float sum = t4.x + t4.y + t4.z + t4.w;
    const size_t idx = (size_t)kh * NN + i0 + j2;
    if (val == 0) {
      float sp = sum * LOG2E;
      Ap[idx] = fexp2(sp);
      A5p[idx] = fexp2(0.2f * sp);
    } else if (val == 1) {
      float dp = sum * LOG2E;
      Bp[idx] = fexp2(dp);
      B5p[idx] = fexp2(0.2f * dp);
    } else if (val == 2) {
      G0p[idx] = sum;
    } else {
      G1p[idx] = sum;
    }
  }
}

// ---------------------------------------------------------------------------
// Phase 2: partial softmax sums over a 512-j chunk, 16 rows per block.
// grid (NU/16, K*JSPLIT) = (250, 16), block 256 = 4 waves.
// Lane = (jsub<<4) | row. LDS: 4 planar planes {B,B5,G0,G1} x 4h x 512 = 32 KB.
// 512-j chunk (vs 256) halves per-j staging traffic + epilogue + P size.
// Inner loop: packed-f32 (v_pk_*):
//   e = max(A*B, A5*B5)  [== exp2(leaky(s)), exact identity]
//   pa = adj*e; l += pa; a_c += pa*g_c     — on vf2 j-pairs.
// Adjacency: 8 vf4 nontemporal prefetch per thread (stream-once, no L2 evict).
// ---------------------------------------------------------------------------
__global__ __launch_bounds__(256) void gat_phase2(
    const float* __restrict__ adj, const float* __restrict__ Ap,
    const float* __restrict__ A5p, const float* __restrict__ Bp,
    const float* __restrict__ B5p, const float* __restrict__ G0p,
    const float* __restrict__ G1p, float* __restrict__ P) {
  const int k = blockIdx.y >> 3;
  const int chunk = blockIdx.y & 7;
  const int r0 = blockIdx.x * 16;
  const int tid = threadIdx.x;
  const int wave = tid >> 6;
  const int lane = tid & 63;
  const int row = lane & 15;
  const int jsub = lane >> 4;
  const int i = r0 + row;
  const int j0 = chunk * JCHUNK;

  __shared__ float lds[4][HH][JCHUNK];  // B,B5,G0,G1 planes: 32 KB

  {  // stage 2048 vf4; per step the plane index is uniform (= step>>1)
    const float* plane_src[4] = {Bp, B5p, G0p, G1p};
#pragma unroll
    for (int step = 0; step < 8; ++step) {
      const int wi = ((step & 1) << 8) | tid;  // 0..511 vf4 within plane
      const int h = wi >> 7;
      const int pos = (wi & 127) * 4;
      vf4 v = *(const vf4*)(plane_src[step >> 1] +
                            (size_t)(k * HH + h) * NN + j0 + pos);
      *(vf4*)&lds[step >> 1][h][pos] = v;
    }
  }

  // adjacency prefetch: 8 tiles per wave, all issued before the barrier
  const float* arow =
      adj + (size_t)k * NN * NN + (size_t)i * NN + j0 + jsub * 4;
  vf4 aj[8];
#pragma unroll
  for (int q = 0; q < 8; ++q)
    aj[q] = __builtin_nontemporal_load((const vf4*)(arow + (wave + q * 4) * 16));

  vf2 Apk[4], A5pk[4];
#pragma unroll
  for (int h = 0; h < 4; ++h) {
    const size_t ia = (size_t)(k * HH + h) * NN + i;
    float a = Ap[ia];
    float a5 = A5p[ia];
    Apk[h] = (vf2){a, a};
    A5pk[h] = (vf2){a5, a5};
  }

  vf2 l2[4], a02[4], a12[4];
#pragma unroll
  for (int h = 0; h < 4; ++h) {
    l2[h] = (vf2){0.0f, 0.0f};
    a02[h] = (vf2){0.0f, 0.0f};
    a12[h] = (vf2){0.0f, 0.0f};
  }

  __syncthreads();

  // 32 tiles of 16 j; wave handles t = wave + s*4, s=0..7.
#pragma unroll
  for (int s = 0; s < 8; ++s) {
    const int t = wave + s * 4;
    const vf4 av = aj[s];
    const vf2 av01 = (vf2){av.x, av.y};
    const vf2 av23 = (vf2){av.z, av.w};
    const int jl = t * 16 + jsub * 4;
#pragma unroll
    for (int h = 0; h < 4; ++h) {
      vf4 Bv = *(const vf4*)&lds[0][h][jl];
      vf4 B5v = *(const vf4*)&lds[1][h][jl];
      vf4 G0v = *(const vf4*)&lds[2][h][jl];
      vf4 G1v = *(const vf4*)&lds[3][h][jl];

      vf2 m01 = Apk[h] * (vf2){Bv.x, Bv.y};    // v_pk_mul_f32
      vf2 n01 = A5pk[h] * (vf2){B5v.x, B5v.y};
      vf2 e01 = (vf2){fmaxf(m01.x, n01.x), fmaxf(m01.y, n01.y)};
      vf2 pa01 = e01 * av01;
      l2[h] += pa01;                            // v_pk_add_f32
      a02[h] += pa01 * (vf2){G0v.x, G0v.y};     // v_pk_fma_f32
      a12[h] += pa01 * (vf2){G1v.x, G1v.y};

      vf2 m23 = Apk[h] * (vf2){Bv.z, Bv.w};
      vf2 n23 = A5pk[h] * (vf2){B5v.z, B5v.w};
      vf2 e23 = (vf2){fmaxf(m23.x, n23.x), fmaxf(m23.y, n23.y)};
      vf2 pa23 = e23 * av23;
      l2[h] += pa23;
      a02[h] += pa23 * (vf2){G0v.z, G0v.w};
      a12[h] += pa23 * (vf2){G1v.z, G1v.w};
    }
  }

  // horizontal j-pair collapse, then butterfly over jsub (lane bits 4,5)
  float l[4], a0[4], a1[4];
#pragma unroll
  for (int h = 0; h < 4; ++h) {
    l[h] = l2[h].x + l2[h].y;
    a0[h] = a02[h].x + a02[h].y;
    a1[h] = a12[h].x + a12[h].y;
  }
#pragma unroll
  for (int h = 0; h < 4; ++h) {
    l[h] += __shfl_xor(l[h], 16, 64);
    l[h] += __shfl_xor(l[h], 32, 64);
    a0[h] += __shfl_xor(a0[h], 16, 64);
    a0[h] += __shfl_xor(a0[h], 32, 64);
    a1[h] += __shfl_xor(a1[h], 16, 64);
    a1[h] += __shfl_xor(a1[h], 32, 64);
  }

  // cross-wave combine: sred[wave][v][row], v = h*3+c
  __shared__ float sred[4][12][16];
  if (lane < 16) {
#pragma unroll
    for (int h = 0; h < 4; ++h) {
      sred[wave][h * 3 + 0][row] = l[h];
      sred[wave][h * 3 + 1][row] = a0[h];
      sred[wave][h * 3 + 2][row] = a1[h];
    }
  }
  __syncthreads();
  if (tid < 192) {
    const int v = tid >> 4;  // 0..11 = h*3+c
    const int rr = tid & 15;
    float sum =
        sred[0][v][rr] + sred[1][v][rr] + sred[2][v][rr] + sred[3][v][rr];
    const int h = v / 3, c = v % 3;
    // P layout: [k][chunk][h][{l,a0,a1}][i]
    size_t base =
        ((((size_t)(k * JSPLIT + chunk) * HH + h) * 3 + c)) * NU + (r0 + rr);
    P[base] = sum;
  }
}

// ---------------------------------------------------------------------------
// Phase 3: combine chunk partials, divide, mean heads, sum kinds, +bias,
// log_softmax over C=2. g = tid>>5 (wave-half-uniform plane) -> 128B
// coalesced P reads; LDS combine across the 8 (k,h) groups.
// ---------------------------------------------------------------------------
__global__ __launch_bounds__(256) void gat_phase3(
    const float* __restrict__ P, const float* __restrict__ fc_b,
    float* __restrict__ out) {
  const int tid = threadIdx.x;
  const int il = tid & 31;
  const int g = tid >> 5;  // 0..7 = (k,h), uniform per 32-lane half
  const int i = blockIdx.x * 32 + il;  // 125*32 == NU exactly
  const int k = g >> 2, h = g & 3;

  float ls = 0.0f, a0 = 0.0f, a1 = 0.0f;
#pragma unroll
  for (int ch = 0; ch < JSPLIT; ++ch) {
    size_t b = (((size_t)(k * JSPLIT + ch) * HH + h) * 3) * NU + i;
    ls += P[b];
    a0 += P[b + NU];
    a1 += P[b + 2 * (size_t)NU];
  }
  float inv = 1.0f / ls;
  float p0 = 0.25f * a0 * inv;
  float p1 = 0.25f * a1 * inv;

  __shared__ float s0[8][33], s1[8][33];
  s0[g][il] = p0;
  s1[g][il] = p1;
  __syncthreads();

  if (tid < 32) {
    float l0 = fc_b[0], l1 = fc_b[1];
#pragma unroll
    for (int g2 = 0; g2 < 8; ++g2) {
      l0 += s0[g2][tid];
      l1 += s1[g2][tid];
    }
    const int io = blockIdx.x * 32 + tid;
    float m = fmaxf(l0, l1);
    float lse = m + logf(expf(l0 - m) + expf(l1 - m));
    vf2 r = {l0 - lse, l1 - lse};
    *(vf2*)(out + (size_t)io * CC) = r;
  }
}

extern "C" void kernel_launch(void* const* d_in, const int* in_sizes, int n_in,
                              void* d_out, int out_size, void* d_ws, size_t ws_size,
                              hipStream_t stream) {
  const float* hsrc  = (const float*)d_in[0];  // (1,4096,64)
  const float* hadj  = (const float*)d_in[1];  // (2,1,4096,4096)
  const float* w     = (const float*)d_in[2];  // (2,4,64,64)
  const float* a_src = (const float*)d_in[3];  // (2,4,64,1)
  const float* a_dst = (const float*)d_in[4];  // (2,4,64,1)
  const float* fc_w  = (const float*)d_in[5];  // (2,128)
  const float* fc_b  = (const float*)d_in[6];  // (2,)
  float* out = (float*)d_out;                  // (1,4000,2) fp32

  char* ws = (char*)d_ws;
  // planar KH*NN planes, 128 KB each
  float* Ap  = (float*)(ws + 0);
  float* A5p = (float*)(ws + 131072);
  float* Bp  = (float*)(ws + 262144);
  float* B5p = (float*)(ws + 393216);
  float* G0p = (float*)(ws + 524288);
  float* G1p = (float*)(ws + 655360);
  float* P   = (float*)(ws + 786432);  // K*JSPLIT*H*3*NU floats (~3 MB)

  dim3 g1(NN / 64, KK * HH);
  gat_phase1<<<g1, 256, 0, stream>>>(hsrc, w, a_src, a_dst, fc_w,
                                     Ap, A5p, Bp, B5p, G0p, G1p);
  dim3 g2(NU / 16, KK * JSPLIT);
  gat_phase2<<<g2, 256, 0, stream>>>(hadj, Ap, A5p, Bp, B5p, G0p, G1p, P);
  gat_phase3<<<NU / 32, 256, 0, stream>>>(P, fc_b, out);
}

// Round 3
// 228.547 us; speedup vs baseline: 1.0032x; 1.0032x over previous
//
#include <hip/hip_runtime.h>
#include <math.h>

constexpr int KK = 2;
constexpr int HH = 4;
constexpr int NN = 4096;
constexpr int DD = 64;
constexpr int OO = 64;
constexpr int NU = 4000;
constexpr int CC = 2;
constexpr int JSPLIT = 16;
constexpr int JCHUNK = NN / JSPLIT;  // 256
constexpr float LOG2E = 1.44269504088896340736f;

typedef float vf4 __attribute__((ext_vector_type(4)));
typedef float vf2 __attribute__((ext_vector_type(2)));

__device__ __forceinline__ float fexp2(float x) {
#if __has_builtin(__builtin_amdgcn_exp2f)
  return __builtin_amdgcn_exp2f(x);
#else
  return exp2f(x);
#endif
}
__device__ __forceinline__ float frcp(float x) {
#if __has_builtin(__builtin_amdgcn_rcpf)
  return __builtin_amdgcn_rcpf(x);
#else
  return 1.0f / x;
#endif
}
__device__ __forceinline__ float ftanh(float x) {
  float e = fexp2(x * (2.0f * LOG2E));
  return 1.0f - 2.0f * frcp(e + 1.0f);
}

// ---------------------------------------------------------------------------
// Phase 1: per (k,h): hp = h @ w (4096x64 @ 64x64); per node n, PLANAR outputs:
//   Ap [kh][n] = 2^src'      A5p[kh][n] = 2^(0.2 src')   (src' = tanh-dot * log2e)
//   Bp [kh][n] = 2^dst'      B5p[kh][n] = 2^(0.2 dst')
//   G0p[kh][n] = hp_n.fc_w0  G1p[kh][n] = hp_n.fc_w1
// Factorized leaky-softmax: exp2(max(s,0.2s)) = max(A*B, A5*B5).
// grid (64, K*H), block 256. Thread = 4 rows x 4 o tile; LDS transpose epi.
// ---------------------------------------------------------------------------
__global__ __launch_bounds__(256) void gat_phase1(
    const float* __restrict__ hsrc, const float* __restrict__ w,
    const float* __restrict__ a_src, const float* __restrict__ a_dst,
    const float* __restrict__ fc_w,
    float* __restrict__ Ap, float* __restrict__ A5p,
    float* __restrict__ Bp, float* __restrict__ B5p,
    float* __restrict__ G0p, float* __restrict__ G1p) {
  const int kh = blockIdx.y;  // 0..7
  const int k = kh >> 2;
  const int i0 = blockIdx.x * 64;
  const int tid = threadIdx.x;

  __shared__ float h_s[DD][68];
  __shared__ float w_s[DD][OO];
  __shared__ float part[4][64][17];  // [val][row][og], padded

  {
    const vf4* wp = (const vf4*)(w + (size_t)kh * DD * OO);
    vf4* ws4 = (vf4*)w_s;
    for (int t = tid; t < DD * OO / 4; t += 256) ws4[t] = wp[t];
  }
  for (int t = tid; t < 1024; t += 256) {
    const int row = t >> 4;
    const int f4 = (t & 15) * 4;
    vf4 v = *(const vf4*)(hsrc + (size_t)(i0 + row) * DD + f4);
    h_s[f4 + 0][row] = v.x;
    h_s[f4 + 1][row] = v.y;
    h_s[f4 + 2][row] = v.z;
    h_s[f4 + 3][row] = v.w;
  }
  __syncthreads();

  const int og = tid & 15;
  const int rg = tid >> 4;
  const int o0 = og * 4;
  const int r0 = rg * 4;

  float hp[4][4];
#pragma unroll
  for (int j = 0; j < 4; ++j)
#pragma unroll
    for (int u = 0; u < 4; ++u) hp[j][u] = 0.0f;

#pragma unroll 8
  for (int f = 0; f < DD; ++f) {
    vf4 hv = *(const vf4*)&h_s[f][r0];
    vf4 wv = *(const vf4*)&w_s[f][o0];
    hp[0][0] = fmaf(hv.x, wv.x, hp[0][0]);
    hp[0][1] = fmaf(hv.x, wv.y, hp[0][1]);
    hp[0][2] = fmaf(hv.x, wv.z, hp[0][2]);
    hp[0][3] = fmaf(hv.x, wv.w, hp[0][3]);
    hp[1][0] = fmaf(hv.y, wv.x, hp[1][0]);
    hp[1][1] = fmaf(hv.y, wv.y, hp[1][1]);
    hp[1][2] = fmaf(hv.y, wv.z, hp[1][2]);
    hp[1][3] = fmaf(hv.y, wv.w, hp[1][3]);
    hp[2][0] = fmaf(hv.z, wv.x, hp[2][0]);
    hp[2][1] = fmaf(hv.z, wv.y, hp[2][1]);
    hp[2][2] = fmaf(hv.z, wv.z, hp[2][2]);
    hp[2][3] = fmaf(hv.z, wv.w, hp[2][3]);
    hp[3][0] = fmaf(hv.w, wv.x, hp[3][0]);
    hp[3][1] = fmaf(hv.w, wv.y, hp[3][1]);
    hp[3][2] = fmaf(hv.w, wv.z, hp[3][2]);
    hp[3][3] = fmaf(hv.w, wv.w, hp[3][3]);
  }

  float as[4], ad[4], f0[4], f1[4];
#pragma unroll
  for (int u = 0; u < 4; ++u) {
    as[u] = a_src[kh * OO + o0 + u];
    ad[u] = a_dst[kh * OO + o0 + u];
    f0[u] = fc_w[0 * (KK * OO) + k * OO + o0 + u];
    f1[u] = fc_w[1 * (KK * OO) + k * OO + o0 + u];
  }

#pragma unroll
  for (int j = 0; j < 4; ++j) {
    float sp = 0.0f, dp = 0.0f, g0 = 0.0f, g1 = 0.0f;
#pragma unroll
    for (int u = 0; u < 4; ++u) {
      float v = hp[j][u];
      float t = ftanh(v);
      sp = fmaf(t, as[u], sp);
      dp = fmaf(t, ad[u], dp);
      g0 = fmaf(v, f0[u], g0);
      g1 = fmaf(v, f1[u], g1);
    }
    part[0][r0 + j][og] = sp;
    part[1][r0 + j][og] = dp;
    part[2][r0 + j][og] = g0;
    part[3][r0 + j][og] = g1;
  }
  __syncthreads();

  {  // wave = val plane (uniform branch), lane = row j2; sum 16 og-partials
    const int val = tid >> 6;
    const int j2 = tid & 63;
    const float* pr = &part[val][j2][0];
    vf4 s0 = *(const vf4*)(pr + 0);
    vf4 s1 = *(const vf4*)(pr + 4);
    vf4 s2 = *(const vf4*)(pr + 8);
    vf4 s3 = *(const vf4*)(pr + 12);
    vf4 t4 = s0 + s1 + s2 + s3;
    float sum = t4.x + t4.y + t4.z + t4.w;
    const size_t idx = (size_t)kh * NN + i0 + j2;
    if (val == 0) {
      float sp = sum * LOG2E;
      Ap[idx] = fexp2(sp);
      A5p[idx] = fexp2(0.2f * sp);
    } else if (val == 1) {
      float dp = sum * LOG2E;
      Bp[idx] = fexp2(dp);
      B5p[idx] = fexp2(0.2f * dp);
    } else if (val == 2) {
      G0p[idx] = sum;
    } else {
      G1p[idx] = sum;
    }
  }
}

// ---------------------------------------------------------------------------
// Phase 2: partial softmax sums over a 256-j chunk, 32 rows per block.
// grid (NU/32, K*JSPLIT) = (125, 32), block 256 = 4 waves.
// Lane = (jsub<<4) | row; each thread owns TWO rows (r, r+16) so every
// LDS plane read (ds_read_b128) is amortized over 2 rows — LDS traffic
// halves vs 1-row blocks (phase2 was LDS-return-bandwidth bound).
// LDS: 4 planar planes {B,B5,G0,G1} x 4h x 256 = 16 KB (+6 KB sred).
// Scalar inner loop (no pk-splat) keeps VGPR <= ~120 -> 16 waves/CU.
//   e = max(A*B, A5*B5)  [== exp2(leaky(s)), exact identity]
//   pa = adj*e; l += pa; a_c += pa*g_c
// Adjacency: nontemporal vf4 (stream-once; don't evict planes/P from L2).
// ---------------------------------------------------------------------------
__global__ __launch_bounds__(256) void gat_phase2(
    const float* __restrict__ adj, const float* __restrict__ Ap,
    const float* __restrict__ A5p, const float* __restrict__ Bp,
    const float* __restrict__ B5p, const float* __restrict__ G0p,
    const float* __restrict__ G1p, float* __restrict__ P) {
  const int k = blockIdx.y >> 4;
  const int chunk = blockIdx.y & 15;
  const int r0 = blockIdx.x * 32;
  const int tid = threadIdx.x;
  const int wave = tid >> 6;
  const int lane = tid & 63;
  const int row = lane & 15;
  const int jsub = lane >> 4;
  const int i0r = r0 + row;       // first owned row
  const int i1r = r0 + 16 + row;  // second owned row
  const int j0 = chunk * JCHUNK;

  __shared__ float lds[4][HH][JCHUNK];  // B,B5,G0,G1 planes: 16 KB

  {  // stage 1024 vf4; plane index uniform per step (= step)
    const float* plane_src[4] = {Bp, B5p, G0p, G1p};
#pragma unroll
    for (int step = 0; step < 4; ++step) {
      const int h = (tid >> 6) & 3;
      const int pos = (tid & 63) * 4;
      vf4 v = *(const vf4*)(plane_src[step] +
                            (size_t)(k * HH + h) * NN + j0 + pos);
      *(vf4*)&lds[step][h][pos] = v;
    }
  }

  // adjacency prefetch: 2 rows x 4 tiles, issued before the barrier
  const size_t abase = (size_t)k * NN * NN + j0 + jsub * 4;
  const float* ar0 = adj + abase + (size_t)i0r * NN;
  const float* ar1 = adj + abase + (size_t)i1r * NN;
  vf4 aj0[4], aj1[4];
#pragma unroll
  for (int q = 0; q < 4; ++q) {
    aj0[q] = __builtin_nontemporal_load((const vf4*)(ar0 + (wave + q * 4) * 16));
    aj1[q] = __builtin_nontemporal_load((const vf4*)(ar1 + (wave + q * 4) * 16));
  }

  // per-row A values (plain scalars; per-lane, rows differ across lanes)
  float A0[4], A50[4], A1[4], A51[4];
#pragma unroll
  for (int h = 0; h < 4; ++h) {
    const size_t pb = (size_t)(k * HH + h) * NN;
    A0[h] = Ap[pb + i0r];
    A50[h] = A5p[pb + i0r];
    A1[h] = Ap[pb + i1r];
    A51[h] = A5p[pb + i1r];
  }

  float l[2][4], a0[2][4], a1[2][4];
#pragma unroll
  for (int r = 0; r < 2; ++r)
#pragma unroll
    for (int h = 0; h < 4; ++h) {
      l[r][h] = 0.0f;
      a0[r][h] = 0.0f;
      a1[r][h] = 0.0f;
    }

  __syncthreads();

  // 16 tiles of 16 j; wave handles t = wave + s*4, s=0..3.
#pragma unroll
  for (int s = 0; s < 4; ++s) {
    const int t = wave + s * 4;
    const vf4 av0 = aj0[s];
    const vf4 av1 = aj1[s];
    const int jl = t * 16 + jsub * 4;
#pragma unroll
    for (int h = 0; h < 4; ++h) {
      vf4 Bv = *(const vf4*)&lds[0][h][jl];
      vf4 B5v = *(const vf4*)&lds[1][h][jl];
      vf4 G0v = *(const vf4*)&lds[2][h][jl];
      vf4 G1v = *(const vf4*)&lds[3][h][jl];
#pragma unroll
      for (int jj = 0; jj < 4; ++jj) {
        const float b = Bv[jj], b5 = B5v[jj];
        const float g0 = G0v[jj], g1 = G1v[jj];
        float e0 = fmaxf(A0[h] * b, A50[h] * b5);
        float pa0 = e0 * av0[jj];
        l[0][h] += pa0;
        a0[0][h] = fmaf(pa0, g0, a0[0][h]);
        a1[0][h] = fmaf(pa0, g1, a1[0][h]);
        float e1 = fmaxf(A1[h] * b, A51[h] * b5);
        float pa1 = e1 * av1[jj];
        l[1][h] += pa1;
        a0[1][h] = fmaf(pa1, g0, a0[1][h]);
        a1[1][h] = fmaf(pa1, g1, a1[1][h]);
      }
    }
  }

  // butterfly over jsub (lane bits 4,5): every lane ends with full j-sums
#pragma unroll
  for (int r = 0; r < 2; ++r)
#pragma unroll
    for (int h = 0; h < 4; ++h) {
      l[r][h] += __shfl_xor(l[r][h], 16, 64);
      l[r][h] += __shfl_xor(l[r][h], 32, 64);
      a0[r][h] += __shfl_xor(a0[r][h], 16, 64);
      a0[r][h] += __shfl_xor(a0[r][h], 32, 64);
      a1[r][h] += __shfl_xor(a1[r][h], 16, 64);
      a1[r][h] += __shfl_xor(a1[r][h], 32, 64);
    }

  // cross-wave combine: sred[wave][v][rr], v = h*3+c, rr = row + 16*half
  __shared__ float sred[4][12][32];
  if (lane < 32) {
    const int half = lane >> 4;  // which of this thread's two rows to write
#pragma unroll
    for (int h = 0; h < 4; ++h) {
      sred[wave][h * 3 + 0][row + 16 * half] = l[half][h];
      sred[wave][h * 3 + 1][row + 16 * half] = a0[half][h];
      sred[wave][h * 3 + 2][row + 16 * half] = a1[half][h];
    }
  }
  __syncthreads();
  if (tid < 192) {
    const int v = tid >> 4;  // 0..11 = h*3+c
    const int h = v / 3, c = v % 3;
    const size_t pbase =
        ((((size_t)(k * JSPLIT + chunk) * HH + h) * 3 + c)) * NU + r0;
#pragma unroll
    for (int half = 0; half < 2; ++half) {
      const int rr = (tid & 15) + 16 * half;
      float sum =
          sred[0][v][rr] + sred[1][v][rr] + sred[2][v][rr] + sred[3][v][rr];
      P[pbase + rr] = sum;
    }
  }
}

// ---------------------------------------------------------------------------
// Phase 3: combine chunk partials, divide, mean heads, sum kinds, +bias,
// log_softmax over C=2. g = tid>>5 (wave-half-uniform plane) -> 128B
// coalesced P reads; LDS combine across the 8 (k,h) groups.
// ---------------------------------------------------------------------------
__global__ __launch_bounds__(256) void gat_phase3(
    const float* __restrict__ P, const float* __restrict__ fc_b,
    float* __restrict__ out) {
  const int tid = threadIdx.x;
  const int il = tid & 31;
  const int g = tid >> 5;  // 0..7 = (k,h), uniform per 32-lane half
  const int i = blockIdx.x * 32 + il;  // 125*32 == NU exactly
  const int k = g >> 2, h = g & 3;

  float ls = 0.0f, a0 = 0.0f, a1 = 0.0f;
#pragma unroll
  for (int ch = 0; ch < JSPLIT; ++ch) {
    size_t b = (((size_t)(k * JSPLIT + ch) * HH + h) * 3) * NU + i;
    ls += P[b];
    a0 += P[b + NU];
    a1 += P[b + 2 * (size_t)NU];
  }
  float inv = 1.0f / ls;
  float p0 = 0.25f * a0 * inv;
  float p1 = 0.25f * a1 * inv;

  __shared__ float s0[8][33], s1[8][33];
  s0[g][il] = p0;
  s1[g][il] = p1;
  __syncthreads();

  if (tid < 32) {
    float l0 = fc_b[0], l1 = fc_b[1];
#pragma unroll
    for (int g2 = 0; g2 < 8; ++g2) {
      l0 += s0[g2][tid];
      l1 += s1[g2][tid];
    }
    const int io = blockIdx.x * 32 + tid;
    float m = fmaxf(l0, l1);
    float lse = m + logf(expf(l0 - m) + expf(l1 - m));
    vf2 r = {l0 - lse, l1 - lse};
    *(vf2*)(out + (size_t)io * CC) = r;
  }
}

extern "C" void kernel_launch(void* const* d_in, const int* in_sizes, int n_in,
                              void* d_out, int out_size, void* d_ws, size_t ws_size,
                              hipStream_t stream) {
  const float* hsrc  = (const float*)d_in[0];  // (1,4096,64)
  const float* hadj  = (const float*)d_in[1];  // (2,1,4096,4096)
  const float* w     = (const float*)d_in[2];  // (2,4,64,64)
  const float* a_src = (const float*)d_in[3];  // (2,4,64,1)
  const float* a_dst = (const float*)d_in[4];  // (2,4,64,1)
  const float* fc_w  = (const float*)d_in[5];  // (2,128)
  const float* fc_b  = (const float*)d_in[6];  // (2,)
  float* out = (float*)d_out;                  // (1,4000,2) fp32

  char* ws = (char*)d_ws;
  // planar KH*NN planes, 128 KB each
  float* Ap  = (float*)(ws + 0);
  float* A5p = (float*)(ws + 131072);
  float* Bp  = (float*)(ws + 262144);
  float* B5p = (float*)(ws + 393216);
  float* G0p = (float*)(ws + 524288);
  float* G1p = (float*)(ws + 655360);
  float* P   = (float*)(ws + 786432);  // K*JSPLIT*H*3*NU floats (~6.1 MB)

  dim3 g1(NN / 64, KK * HH);
  gat_phase1<<<g1, 256, 0, stream>>>(hsrc, w, a_src, a_dst, fc_w,
                                     Ap, A5p, Bp, B5p, G0p, G1p);
  dim3 g2(NU / 32, KK * JSPLIT);
  gat_phase2<<<g2, 256, 0, stream>>>(hadj, Ap, A5p, Bp, B5p, G0p, G1p, P);
  gat_phase3<<<NU / 32, 256, 0, stream>>>(P, fc_b, out);
}

// Round 4
// 222.482 us; speedup vs baseline: 1.0306x; 1.0273x over previous
//
#include <hip/hip_runtime.h>
#include <math.h>

constexpr int KK = 2;
constexpr int HH = 4;
constexpr int NN = 4096;
constexpr int DD = 64;
constexpr int OO = 64;
constexpr int NU = 4000;
constexpr int CC = 2;
constexpr int JSPLIT = 16;
constexpr int JCHUNK = NN / JSPLIT;  // 256
constexpr float LOG2E = 1.44269504088896340736f;

typedef float vf4 __attribute__((ext_vector_type(4)));
typedef float vf2 __attribute__((ext_vector_type(2)));

__device__ __forceinline__ float fexp2(float x) {
#if __has_builtin(__builtin_amdgcn_exp2f)
  return __builtin_amdgcn_exp2f(x);
#else
  return exp2f(x);
#endif
}
__device__ __forceinline__ float frcp(float x) {
#if __has_builtin(__builtin_amdgcn_rcpf)
  return __builtin_amdgcn_rcpf(x);
#else
  return 1.0f / x;
#endif
}
__device__ __forceinline__ float ftanh(float x) {
  float e = fexp2(x * (2.0f * LOG2E));
  return 1.0f - 2.0f * frcp(e + 1.0f);
}

// ---------------------------------------------------------------------------
// Phase 1: per (k,h): hp = h @ w (4096x64 @ 64x64); per node n, PLANAR outputs:
//   Ap [kh][n] = 2^src'      A5p[kh][n] = 2^(0.2 src')   (src' = tanh-dot * log2e)
//   Bp [kh][n] = 2^dst'      B5p[kh][n] = 2^(0.2 dst')
//   G0p[kh][n] = hp_n.fc_w0  G1p[kh][n] = hp_n.fc_w1
// Factorized leaky-softmax: exp2(max(s,0.2s)) = max(A*B, A5*B5).
// grid (64, K*H), block 256. Thread = 4 rows x 4 o tile; LDS transpose epi.
// ---------------------------------------------------------------------------
__global__ __launch_bounds__(256) void gat_phase1(
    const float* __restrict__ hsrc, const float* __restrict__ w,
    const float* __restrict__ a_src, const float* __restrict__ a_dst,
    const float* __restrict__ fc_w,
    float* __restrict__ Ap, float* __restrict__ A5p,
    float* __restrict__ Bp, float* __restrict__ B5p,
    float* __restrict__ G0p, float* __restrict__ G1p) {
  const int kh = blockIdx.y;  // 0..7
  const int k = kh >> 2;
  const int i0 = blockIdx.x * 64;
  const int tid = threadIdx.x;

  __shared__ float h_s[DD][68];
  __shared__ float w_s[DD][OO];
  __shared__ float part[4][64][17];  // [val][row][og], padded

  {
    const vf4* wp = (const vf4*)(w + (size_t)kh * DD * OO);
    vf4* ws4 = (vf4*)w_s;
    for (int t = tid; t < DD * OO / 4; t += 256) ws4[t] = wp[t];
  }
  for (int t = tid; t < 1024; t += 256) {
    const int row = t >> 4;
    const int f4 = (t & 15) * 4;
    vf4 v = *(const vf4*)(hsrc + (size_t)(i0 + row) * DD + f4);
    h_s[f4 + 0][row] = v.x;
    h_s[f4 + 1][row] = v.y;
    h_s[f4 + 2][row] = v.z;
    h_s[f4 + 3][row] = v.w;
  }
  __syncthreads();

  const int og = tid & 15;
  const int rg = tid >> 4;
  const int o0 = og * 4;
  const int r0 = rg * 4;

  float hp[4][4];
#pragma unroll
  for (int j = 0; j < 4; ++j)
#pragma unroll
    for (int u = 0; u < 4; ++u) hp[j][u] = 0.0f;

#pragma unroll 8
  for (int f = 0; f < DD; ++f) {
    vf4 hv = *(const vf4*)&h_s[f][r0];
    vf4 wv = *(const vf4*)&w_s[f][o0];
    hp[0][0] = fmaf(hv.x, wv.x, hp[0][0]);
    hp[0][1] = fmaf(hv.x, wv.y, hp[0][1]);
    hp[0][2] = fmaf(hv.x, wv.z, hp[0][2]);
    hp[0][3] = fmaf(hv.x, wv.w, hp[0][3]);
    hp[1][0] = fmaf(hv.y, wv.x, hp[1][0]);
    hp[1][1] = fmaf(hv.y, wv.y, hp[1][1]);
    hp[1][2] = fmaf(hv.y, wv.z, hp[1][2]);
    hp[1][3] = fmaf(hv.y, wv.w, hp[1][3]);
    hp[2][0] = fmaf(hv.z, wv.x, hp[2][0]);
    hp[2][1] = fmaf(hv.z, wv.y, hp[2][1]);
    hp[2][2] = fmaf(hv.z, wv.z, hp[2][2]);
    hp[2][3] = fmaf(hv.z, wv.w, hp[2][3]);
    hp[3][0] = fmaf(hv.w, wv.x, hp[3][0]);
    hp[3][1] = fmaf(hv.w, wv.y, hp[3][1]);
    hp[3][2] = fmaf(hv.w, wv.z, hp[3][2]);
    hp[3][3] = fmaf(hv.w, wv.w, hp[3][3]);
  }

  float as[4], ad[4], f0[4], f1[4];
#pragma unroll
  for (int u = 0; u < 4; ++u) {
    as[u] = a_src[kh * OO + o0 + u];
    ad[u] = a_dst[kh * OO + o0 + u];
    f0[u] = fc_w[0 * (KK * OO) + k * OO + o0 + u];
    f1[u] = fc_w[1 * (KK * OO) + k * OO + o0 + u];
  }

#pragma unroll
  for (int j = 0; j < 4; ++j) {
    float sp = 0.0f, dp = 0.0f, g0 = 0.0f, g1 = 0.0f;
#pragma unroll
    for (int u = 0; u < 4; ++u) {
      float v = hp[j][u];
      float t = ftanh(v);
      sp = fmaf(t, as[u], sp);
      dp = fmaf(t, ad[u], dp);
      g0 = fmaf(v, f0[u], g0);
      g1 = fmaf(v, f1[u], g1);
    }
    part[0][r0 + j][og] = sp;
    part[1][r0 + j][og] = dp;
    part[2][r0 + j][og] = g0;
    part[3][r0 + j][og] = g1;
  }
  __syncthreads();

  {  // wave = val plane (uniform branch), lane = row j2; sum 16 og-partials
    const int val = tid >> 6;
    const int j2 = tid & 63;
    const float* pr = &part[val][j2][0];
    vf4 s0 = *(const vf4*)(pr + 0);
    vf4 s1 = *(const vf4*)(pr + 4);
    vf4 s2 = *(const vf4*)(pr + 8);
    vf4 s3 = *(const vf4*)(pr + 12);
    vf4 t4 = s0 + s1 + s2 + s3;
    float sum = t4.x + t4.y + t4.z + t4.w;
    const size_t idx = (size_t)kh * NN + i0 + j2;
    if (val == 0) {
      float sp = sum * LOG2E;
      Ap[idx] = fexp2(sp);
      A5p[idx] = fexp2(0.2f * sp);
    } else if (val == 1) {
      float dp = sum * LOG2E;
      Bp[idx] = fexp2(dp);
      B5p[idx] = fexp2(0.2f * dp);
    } else if (val == 2) {
      G0p[idx] = sum;
    } else {
      G1p[idx] = sum;
    }
  }
}

// ---------------------------------------------------------------------------
// Phase 2: partial softmax sums over a 256-j chunk, 32 rows per block.
// grid (NU/32, K*JSPLIT) = (125, 32), block 256 = 4 waves.
// Lane = (jsub<<4) | row; each thread owns TWO rows (r, r+16) so every
// LDS plane read (ds_read_b128) is amortized over 2 rows.
// LDS: 4 planar planes {B,B5,G0,G1} x 4h x 256 = 16 KB (+6 KB sred).
// Adjacency: PLAIN vf4 loads (nontemporal hurt: the complementary 64B of
// each 128B line is read by a sibling wave and must survive in L2),
// distance-1 software pipeline (2 tiles in flight, 16 VGPR).
//   e = max(A*B, A5*B5)  [== exp2(leaky(s)), exact identity]
//   pa = adj*e; l += pa; a_c += pa*g_c
// ---------------------------------------------------------------------------
__global__ __launch_bounds__(256) void gat_phase2(
    const float* __restrict__ adj, const float* __restrict__ Ap,
    const float* __restrict__ A5p, const float* __restrict__ Bp,
    const float* __restrict__ B5p, const float* __restrict__ G0p,
    const float* __restrict__ G1p, float* __restrict__ P) {
  const int k = blockIdx.y >> 4;
  const int chunk = blockIdx.y & 15;
  const int r0 = blockIdx.x * 32;
  const int tid = threadIdx.x;
  const int wave = tid >> 6;
  const int lane = tid & 63;
  const int row = lane & 15;
  const int jsub = lane >> 4;
  const int i0r = r0 + row;       // first owned row
  const int i1r = r0 + 16 + row;  // second owned row
  const int j0 = chunk * JCHUNK;

  __shared__ float lds[4][HH][JCHUNK];  // B,B5,G0,G1 planes: 16 KB

  {  // stage 1024 vf4; plane index uniform per step (= step)
    const float* plane_src[4] = {Bp, B5p, G0p, G1p};
#pragma unroll
    for (int step = 0; step < 4; ++step) {
      const int h = (tid >> 6) & 3;
      const int pos = (tid & 63) * 4;
      vf4 v = *(const vf4*)(plane_src[step] +
                            (size_t)(k * HH + h) * NN + j0 + pos);
      *(vf4*)&lds[step][h][pos] = v;
    }
  }

  // per-row A values (per-lane; lanes 0-15 = consecutive rows, coalesced)
  float A0[4], A50[4], A1[4], A51[4];
#pragma unroll
  for (int h = 0; h < 4; ++h) {
    const size_t pb = (size_t)(k * HH + h) * NN;
    A0[h] = Ap[pb + i0r];
    A50[h] = A5p[pb + i0r];
    A1[h] = Ap[pb + i1r];
    A51[h] = A5p[pb + i1r];
  }

  float l[2][4], a0[2][4], a1[2][4];
#pragma unroll
  for (int r = 0; r < 2; ++r)
#pragma unroll
    for (int h = 0; h < 4; ++h) {
      l[r][h] = 0.0f;
      a0[r][h] = 0.0f;
      a1[r][h] = 0.0f;
    }

  const size_t abase = (size_t)k * NN * NN + j0 + jsub * 4;
  const float* ar0 = adj + abase + (size_t)i0r * NN;
  const float* ar1 = adj + abase + (size_t)i1r * NN;

  // pipeline prologue: tile s=0 (t=wave) in flight before the barrier
  vf4 c0 = *(const vf4*)(ar0 + wave * 16);
  vf4 c1 = *(const vf4*)(ar1 + wave * 16);

  __syncthreads();

  // 16 tiles of 16 j; wave handles t = wave + s*4, s=0..3 (dist-1 prefetch).
#pragma unroll
  for (int s = 0; s < 4; ++s) {
    const vf4 av0 = c0;
    const vf4 av1 = c1;
    if (s < 3) {
      c0 = *(const vf4*)(ar0 + (wave + (s + 1) * 4) * 16);
      c1 = *(const vf4*)(ar1 + (wave + (s + 1) * 4) * 16);
    }
    const int jl = (wave + s * 4) * 16 + jsub * 4;
#pragma unroll
    for (int h = 0; h < 4; ++h) {
      vf4 Bv = *(const vf4*)&lds[0][h][jl];
      vf4 B5v = *(const vf4*)&lds[1][h][jl];
      vf4 G0v = *(const vf4*)&lds[2][h][jl];
      vf4 G1v = *(const vf4*)&lds[3][h][jl];
#pragma unroll
      for (int jj = 0; jj < 4; ++jj) {
        const float b = Bv[jj], b5 = B5v[jj];
        const float g0 = G0v[jj], g1 = G1v[jj];
        float e0 = fmaxf(A0[h] * b, A50[h] * b5);
        float pa0 = e0 * av0[jj];
        l[0][h] += pa0;
        a0[0][h] = fmaf(pa0, g0, a0[0][h]);
        a1[0][h] = fmaf(pa0, g1, a1[0][h]);
        float e1 = fmaxf(A1[h] * b, A51[h] * b5);
        float pa1 = e1 * av1[jj];
        l[1][h] += pa1;
        a0[1][h] = fmaf(pa1, g0, a0[1][h]);
        a1[1][h] = fmaf(pa1, g1, a1[1][h]);
      }
    }
  }

  // butterfly over jsub (lane bits 4,5): every lane ends with full j-sums
#pragma unroll
  for (int r = 0; r < 2; ++r)
#pragma unroll
    for (int h = 0; h < 4; ++h) {
      l[r][h] += __shfl_xor(l[r][h], 16, 64);
      l[r][h] += __shfl_xor(l[r][h], 32, 64);
      a0[r][h] += __shfl_xor(a0[r][h], 16, 64);
      a0[r][h] += __shfl_xor(a0[r][h], 32, 64);
      a1[r][h] += __shfl_xor(a1[r][h], 16, 64);
      a1[r][h] += __shfl_xor(a1[r][h], 32, 64);
    }

  // cross-wave combine: sred[wave][v][rr], v = h*3+c, rr = row + 16*half
  __shared__ float sred[4][12][32];
  if (lane < 32) {
    const int half = lane >> 4;  // which of this thread's two rows to write
#pragma unroll
    for (int h = 0; h < 4; ++h) {
      sred[wave][h * 3 + 0][row + 16 * half] = l[half][h];
      sred[wave][h * 3 + 1][row + 16 * half] = a0[half][h];
      sred[wave][h * 3 + 2][row + 16 * half] = a1[half][h];
    }
  }
  __syncthreads();
  if (tid < 192) {
    const int v = tid >> 4;  // 0..11 = h*3+c
    const int h = v / 3, c = v % 3;
    const size_t pbase =
        ((((size_t)(k * JSPLIT + chunk) * HH + h) * 3 + c)) * NU + r0;
#pragma unroll
    for (int half = 0; half < 2; ++half) {
      const int rr = (tid & 15) + 16 * half;
      float sum =
          sred[0][v][rr] + sred[1][v][rr] + sred[2][v][rr] + sred[3][v][rr];
      P[pbase + rr] = sum;
    }
  }
}

// ---------------------------------------------------------------------------
// Phase 3: combine chunk partials, divide, mean heads, sum kinds, +bias,
// log_softmax over C=2. g = tid>>5 (wave-half-uniform plane) -> 128B
// coalesced P reads; LDS combine across the 8 (k,h) groups.
// ---------------------------------------------------------------------------
__global__ __launch_bounds__(256) void gat_phase3(
    const float* __restrict__ P, const float* __restrict__ fc_b,
    float* __restrict__ out) {
  const int tid = threadIdx.x;
  const int il = tid & 31;
  const int g = tid >> 5;  // 0..7 = (k,h), uniform per 32-lane half
  const int i = blockIdx.x * 32 + il;  // 125*32 == NU exactly
  const int k = g >> 2, h = g & 3;

  float ls = 0.0f, a0 = 0.0f, a1 = 0.0f;
#pragma unroll
  for (int ch = 0; ch < JSPLIT; ++ch) {
    size_t b = (((size_t)(k * JSPLIT + ch) * HH + h) * 3) * NU + i;
    ls += P[b];
    a0 += P[b + NU];
    a1 += P[b + 2 * (size_t)NU];
  }
  float inv = 1.0f / ls;
  float p0 = 0.25f * a0 * inv;
  float p1 = 0.25f * a1 * inv;

  __shared__ float s0[8][33], s1[8][33];
  s0[g][il] = p0;
  s1[g][il] = p1;
  __syncthreads();

  if (tid < 32) {
    float l0 = fc_b[0], l1 = fc_b[1];
#pragma unroll
    for (int g2 = 0; g2 < 8; ++g2) {
      l0 += s0[g2][tid];
      l1 += s1[g2][tid];
    }
    const int io = blockIdx.x * 32 + tid;
    float m = fmaxf(l0, l1);
    float lse = m + logf(expf(l0 - m) + expf(l1 - m));
    vf2 r = {l0 - lse, l1 - lse};
    *(vf2*)(out + (size_t)io * CC) = r;
  }
}

extern "C" void kernel_launch(void* const* d_in, const int* in_sizes, int n_in,
                              void* d_out, int out_size, void* d_ws, size_t ws_size,
                              hipStream_t stream) {
  const float* hsrc  = (const float*)d_in[0];  // (1,4096,64)
  const float* hadj  = (const float*)d_in[1];  // (2,1,4096,4096)
  const float* w     = (const float*)d_in[2];  // (2,4,64,64)
  const float* a_src = (const float*)d_in[3];  // (2,4,64,1)
  const float* a_dst = (const float*)d_in[4];  // (2,4,64,1)
  const float* fc_w  = (const float*)d_in[5];  // (2,128)
  const float* fc_b  = (const float*)d_in[6];  // (2,)
  float* out = (float*)d_out;                  // (1,4000,2) fp32

  char* ws = (char*)d_ws;
  // planar KH*NN planes, 128 KB each
  float* Ap  = (float*)(ws + 0);
  float* A5p = (float*)(ws + 131072);
  float* Bp  = (float*)(ws + 262144);
  float* B5p = (float*)(ws + 393216);
  float* G0p = (float*)(ws + 524288);
  float* G1p = (float*)(ws + 655360);
  float* P   = (float*)(ws + 786432);  // K*JSPLIT*H*3*NU floats (~6.1 MB)

  dim3 g1(NN / 64, KK * HH);
  gat_phase1<<<g1, 256, 0, stream>>>(hsrc, w, a_src, a_dst, fc_w,
                                     Ap, A5p, Bp, B5p, G0p, G1p);
  dim3 g2(NU / 32, KK * JSPLIT);
  gat_phase2<<<g2, 256, 0, stream>>>(hadj, Ap, A5p, Bp, B5p, G0p, G1p, P);
  gat_phase3<<<NU / 32, 256, 0, stream>>>(P, fc_b, out);
}

// Round 5
// 222.151 us; speedup vs baseline: 1.0321x; 1.0015x over previous
//
#include <hip/hip_runtime.h>
#include <math.h>

constexpr int KK = 2;
constexpr int HH = 4;
constexpr int NN = 4096;
constexpr int DD = 64;
constexpr int OO = 64;
constexpr int NU = 4000;
constexpr int CC = 2;
constexpr int JSPLIT = 16;
constexpr int JCHUNK = NN / JSPLIT;  // 256
constexpr float LOG2E = 1.44269504088896340736f;

typedef float vf4 __attribute__((ext_vector_type(4)));
typedef float vf2 __attribute__((ext_vector_type(2)));

__device__ __forceinline__ float fexp2(float x) {
#if __has_builtin(__builtin_amdgcn_exp2f)
  return __builtin_amdgcn_exp2f(x);
#else
  return exp2f(x);
#endif
}
__device__ __forceinline__ float frcp(float x) {
#if __has_builtin(__builtin_amdgcn_rcpf)
  return __builtin_amdgcn_rcpf(x);
#else
  return 1.0f / x;
#endif
}
__device__ __forceinline__ float ftanh(float x) {
  float e = fexp2(x * (2.0f * LOG2E));
  return 1.0f - 2.0f * frcp(e + 1.0f);
}

// ---------------------------------------------------------------------------
// Phase 1: per (k,h): hp = h @ w (4096x64 @ 64x64); per node n, PLANAR outputs:
//   Ap [kh][n] = 2^src'      A5p[kh][n] = 2^(0.2 src')   (src' = tanh-dot * log2e)
//   Bp [kh][n] = 2^dst'      B5p[kh][n] = 2^(0.2 dst')
//   G0p[kh][n] = hp_n.fc_w0  G1p[kh][n] = hp_n.fc_w1
// Factorized leaky-softmax: exp2(max(s,0.2s)) = max(A*B, A5*B5).
// grid (64, K*H), block 256. Thread = 4 rows x 4 o tile; LDS transpose epi.
// ---------------------------------------------------------------------------
__global__ __launch_bounds__(256) void gat_phase1(
    const float* __restrict__ hsrc, const float* __restrict__ w,
    const float* __restrict__ a_src, const float* __restrict__ a_dst,
    const float* __restrict__ fc_w,
    float* __restrict__ Ap, float* __restrict__ A5p,
    float* __restrict__ Bp, float* __restrict__ B5p,
    float* __restrict__ G0p, float* __restrict__ G1p) {
  const int kh = blockIdx.y;  // 0..7
  const int k = kh >> 2;
  const int i0 = blockIdx.x * 64;
  const int tid = threadIdx.x;

  __shared__ float h_s[DD][68];
  __shared__ float w_s[DD][OO];
  __shared__ float part[4][64][17];  // [val][row][og], padded

  {
    const vf4* wp = (const vf4*)(w + (size_t)kh * DD * OO);
    vf4* ws4 = (vf4*)w_s;
    for (int t = tid; t < DD * OO / 4; t += 256) ws4[t] = wp[t];
  }
  for (int t = tid; t < 1024; t += 256) {
    const int row = t >> 4;
    const int f4 = (t & 15) * 4;
    vf4 v = *(const vf4*)(hsrc + (size_t)(i0 + row) * DD + f4);
    h_s[f4 + 0][row] = v.x;
    h_s[f4 + 1][row] = v.y;
    h_s[f4 + 2][row] = v.z;
    h_s[f4 + 3][row] = v.w;
  }
  __syncthreads();

  const int og = tid & 15;
  const int rg = tid >> 4;
  const int o0 = og * 4;
  const int r0 = rg * 4;

  float hp[4][4];
#pragma unroll
  for (int j = 0; j < 4; ++j)
#pragma unroll
    for (int u = 0; u < 4; ++u) hp[j][u] = 0.0f;

#pragma unroll 8
  for (int f = 0; f < DD; ++f) {
    vf4 hv = *(const vf4*)&h_s[f][r0];
    vf4 wv = *(const vf4*)&w_s[f][o0];
    hp[0][0] = fmaf(hv.x, wv.x, hp[0][0]);
    hp[0][1] = fmaf(hv.x, wv.y, hp[0][1]);
    hp[0][2] = fmaf(hv.x, wv.z, hp[0][2]);
    hp[0][3] = fmaf(hv.x, wv.w, hp[0][3]);
    hp[1][0] = fmaf(hv.y, wv.x, hp[1][0]);
    hp[1][1] = fmaf(hv.y, wv.y, hp[1][1]);
    hp[1][2] = fmaf(hv.y, wv.z, hp[1][2]);
    hp[1][3] = fmaf(hv.y, wv.w, hp[1][3]);
    hp[2][0] = fmaf(hv.z, wv.x, hp[2][0]);
    hp[2][1] = fmaf(hv.z, wv.y, hp[2][1]);
    hp[2][2] = fmaf(hv.z, wv.z, hp[2][2]);
    hp[2][3] = fmaf(hv.z, wv.w, hp[2][3]);
    hp[3][0] = fmaf(hv.w, wv.x, hp[3][0]);
    hp[3][1] = fmaf(hv.w, wv.y, hp[3][1]);
    hp[3][2] = fmaf(hv.w, wv.z, hp[3][2]);
    hp[3][3] = fmaf(hv.w, wv.w, hp[3][3]);
  }

  float as[4], ad[4], f0[4], f1[4];
#pragma unroll
  for (int u = 0; u < 4; ++u) {
    as[u] = a_src[kh * OO + o0 + u];
    ad[u] = a_dst[kh * OO + o0 + u];
    f0[u] = fc_w[0 * (KK * OO) + k * OO + o0 + u];
    f1[u] = fc_w[1 * (KK * OO) + k * OO + o0 + u];
  }

#pragma unroll
  for (int j = 0; j < 4; ++j) {
    float sp = 0.0f, dp = 0.0f, g0 = 0.0f, g1 = 0.0f;
#pragma unroll
    for (int u = 0; u < 4; ++u) {
      float v = hp[j][u];
      float t = ftanh(v);
      sp = fmaf(t, as[u], sp);
      dp = fmaf(t, ad[u], dp);
      g0 = fmaf(v, f0[u], g0);
      g1 = fmaf(v, f1[u], g1);
    }
    part[0][r0 + j][og] = sp;
    part[1][r0 + j][og] = dp;
    part[2][r0 + j][og] = g0;
    part[3][r0 + j][og] = g1;
  }
  __syncthreads();

  {  // wave = val plane (uniform branch), lane = row j2; sum 16 og-partials
    const int val = tid >> 6;
    const int j2 = tid & 63;
    const float* pr = &part[val][j2][0];
    vf4 s0 = *(const vf4*)(pr + 0);
    vf4 s1 = *(const vf4*)(pr + 4);
    vf4 s2 = *(const vf4*)(pr + 8);
    vf4 s3 = *(const vf4*)(pr + 12);
    vf4 t4 = s0 + s1 + s2 + s3;
    float sum = t4.x + t4.y + t4.z + t4.w;
    const size_t idx = (size_t)kh * NN + i0 + j2;
    if (val == 0) {
      float sp = sum * LOG2E;
      Ap[idx] = fexp2(sp);
      A5p[idx] = fexp2(0.2f * sp);
    } else if (val == 1) {
      float dp = sum * LOG2E;
      Bp[idx] = fexp2(dp);
      B5p[idx] = fexp2(0.2f * dp);
    } else if (val == 2) {
      G0p[idx] = sum;
    } else {
      G1p[idx] = sum;
    }
  }
}

// ---------------------------------------------------------------------------
// Phase 2: partial softmax sums over a 256-j chunk, 32 rows per block.
// grid (NU/32, K*JSPLIT) = (125, 32), block 256 = 4 waves.
// Lane = (jsub<<4) | row; each thread owns TWO rows (r, r+16) packed into
// the two halves of a vf2 -> LDS plane reads amortized over 2 rows AND the
// inner loop runs on v_pk_*_f32 (7 pk-inst per (h,jj) vs 14 scalar):
//   e = max(A*B, A5*B5)  [== exp2(leaky(s)), exact identity]
//   pa = adj*e; l += pa; a_c += pa*g_c      — all packed over the row pair.
// LDS: 4 planar planes {B,B5,G0,G1} x 4h x 256 = 16 KB (+6 KB sred).
// Adjacency: plain vf4 loads (nt hurt: sibling wave reads the other 64B
// of each 128B line), distance-1 software pipeline (2 tiles in flight).
// ---------------------------------------------------------------------------
__global__ __launch_bounds__(256) void gat_phase2(
    const float* __restrict__ adj, const float* __restrict__ Ap,
    const float* __restrict__ A5p, const float* __restrict__ Bp,
    const float* __restrict__ B5p, const float* __restrict__ G0p,
    const float* __restrict__ G1p, float* __restrict__ P) {
  const int k = blockIdx.y >> 4;
  const int chunk = blockIdx.y & 15;
  const int r0 = blockIdx.x * 32;
  const int tid = threadIdx.x;
  const int wave = tid >> 6;
  const int lane = tid & 63;
  const int row = lane & 15;
  const int jsub = lane >> 4;
  const int i0r = r0 + row;       // first owned row  (vf2 lane .x)
  const int i1r = r0 + 16 + row;  // second owned row (vf2 lane .y)
  const int j0 = chunk * JCHUNK;

  __shared__ float lds[4][HH][JCHUNK];  // B,B5,G0,G1 planes: 16 KB

  {  // stage 1024 vf4; plane index uniform per step (= step)
    const float* plane_src[4] = {Bp, B5p, G0p, G1p};
#pragma unroll
    for (int step = 0; step < 4; ++step) {
      const int h = (tid >> 6) & 3;
      const int pos = (tid & 63) * 4;
      vf4 v = *(const vf4*)(plane_src[step] +
                            (size_t)(k * HH + h) * NN + j0 + pos);
      *(vf4*)&lds[step][h][pos] = v;
    }
  }

  // per-row-pair A values, packed {row0, row1}
  vf2 Apk[4], A5pk[4];
#pragma unroll
  for (int h = 0; h < 4; ++h) {
    const size_t pb = (size_t)(k * HH + h) * NN;
    Apk[h] = (vf2){Ap[pb + i0r], Ap[pb + i1r]};
    A5pk[h] = (vf2){A5p[pb + i0r], A5p[pb + i1r]};
  }

  vf2 lp[4], a0p[4], a1p[4];
#pragma unroll
  for (int h = 0; h < 4; ++h) {
    lp[h] = (vf2){0.0f, 0.0f};
    a0p[h] = (vf2){0.0f, 0.0f};
    a1p[h] = (vf2){0.0f, 0.0f};
  }

  const size_t abase = (size_t)k * NN * NN + j0 + jsub * 4;
  const float* ar0 = adj + abase + (size_t)i0r * NN;
  const float* ar1 = adj + abase + (size_t)i1r * NN;

  // pipeline prologue: tile s=0 (t=wave) in flight before the barrier
  vf4 c0 = *(const vf4*)(ar0 + wave * 16);
  vf4 c1 = *(const vf4*)(ar1 + wave * 16);

  __syncthreads();

  // 16 tiles of 16 j; wave handles t = wave + s*4, s=0..3 (dist-1 prefetch).
#pragma unroll
  for (int s = 0; s < 4; ++s) {
    const vf4 av0 = c0;
    const vf4 av1 = c1;
    if (s < 3) {
      c0 = *(const vf4*)(ar0 + (wave + (s + 1) * 4) * 16);
      c1 = *(const vf4*)(ar1 + (wave + (s + 1) * 4) * 16);
    }
    vf2 avp[4];
#pragma unroll
    for (int jj = 0; jj < 4; ++jj) avp[jj] = (vf2){av0[jj], av1[jj]};
    const int jl = (wave + s * 4) * 16 + jsub * 4;
#pragma unroll
    for (int h = 0; h < 4; ++h) {
      vf4 Bv = *(const vf4*)&lds[0][h][jl];
      vf4 B5v = *(const vf4*)&lds[1][h][jl];
      vf4 G0v = *(const vf4*)&lds[2][h][jl];
      vf4 G1v = *(const vf4*)&lds[3][h][jl];
#pragma unroll
      for (int jj = 0; jj < 4; ++jj) {
        vf2 m = Apk[h] * (vf2){Bv[jj], Bv[jj]};     // v_pk_mul_f32
        vf2 n = A5pk[h] * (vf2){B5v[jj], B5v[jj]};
        vf2 e = __builtin_elementwise_max(m, n);    // v_pk_max_f32
        vf2 pa = e * avp[jj];
        lp[h] += pa;                                 // v_pk_add_f32
        a0p[h] += pa * (vf2){G0v[jj], G0v[jj]};      // v_pk_fma_f32
        a1p[h] += pa * (vf2){G1v[jj], G1v[jj]};
      }
    }
  }

  // unpack row pair, then butterfly over jsub (lane bits 4,5)
  float l[2][4], a0[2][4], a1[2][4];
#pragma unroll
  for (int h = 0; h < 4; ++h) {
    l[0][h] = lp[h].x;
    l[1][h] = lp[h].y;
    a0[0][h] = a0p[h].x;
    a0[1][h] = a0p[h].y;
    a1[0][h] = a1p[h].x;
    a1[1][h] = a1p[h].y;
  }
#pragma unroll
  for (int r = 0; r < 2; ++r)
#pragma unroll
    for (int h = 0; h < 4; ++h) {
      l[r][h] += __shfl_xor(l[r][h], 16, 64);
      l[r][h] += __shfl_xor(l[r][h], 32, 64);
      a0[r][h] += __shfl_xor(a0[r][h], 16, 64);
      a0[r][h] += __shfl_xor(a0[r][h], 32, 64);
      a1[r][h] += __shfl_xor(a1[r][h], 16, 64);
      a1[r][h] += __shfl_xor(a1[r][h], 32, 64);
    }

  // cross-wave combine: sred[wave][v][rr], v = h*3+c, rr = row + 16*half
  __shared__ float sred[4][12][32];
  if (lane < 32) {
    const int half = lane >> 4;  // which of this thread's two rows to write
#pragma unroll
    for (int h = 0; h < 4; ++h) {
      sred[wave][h * 3 + 0][row + 16 * half] = l[half][h];
      sred[wave][h * 3 + 1][row + 16 * half] = a0[half][h];
      sred[wave][h * 3 + 2][row + 16 * half] = a1[half][h];
    }
  }
  __syncthreads();
  if (tid < 192) {
    const int v = tid >> 4;  // 0..11 = h*3+c
    const int h = v / 3, c = v % 3;
    const size_t pbase =
        ((((size_t)(k * JSPLIT + chunk) * HH + h) * 3 + c)) * NU + r0;
#pragma unroll
    for (int half = 0; half < 2; ++half) {
      const int rr = (tid & 15) + 16 * half;
      float sum =
          sred[0][v][rr] + sred[1][v][rr] + sred[2][v][rr] + sred[3][v][rr];
      P[pbase + rr] = sum;
    }
  }
}

// ---------------------------------------------------------------------------
// Phase 3: combine chunk partials, divide, mean heads, sum kinds, +bias,
// log_softmax over C=2. g = tid>>5 (wave-half-uniform plane) -> 128B
// coalesced P reads; LDS combine across the 8 (k,h) groups.
// ---------------------------------------------------------------------------
__global__ __launch_bounds__(256) void gat_phase3(
    const float* __restrict__ P, const float* __restrict__ fc_b,
    float* __restrict__ out) {
  const int tid = threadIdx.x;
  const int il = tid & 31;
  const int g = tid >> 5;  // 0..7 = (k,h), uniform per 32-lane half
  const int i = blockIdx.x * 32 + il;  // 125*32 == NU exactly
  const int k = g >> 2, h = g & 3;

  float ls = 0.0f, a0 = 0.0f, a1 = 0.0f;
#pragma unroll
  for (int ch = 0; ch < JSPLIT; ++ch) {
    size_t b = (((size_t)(k * JSPLIT + ch) * HH + h) * 3) * NU + i;
    ls += P[b];
    a0 += P[b + NU];
    a1 += P[b + 2 * (size_t)NU];
  }
  float inv = 1.0f / ls;
  float p0 = 0.25f * a0 * inv;
  float p1 = 0.25f * a1 * inv;

  __shared__ float s0[8][33], s1[8][33];
  s0[g][il] = p0;
  s1[g][il] = p1;
  __syncthreads();

  if (tid < 32) {
    float l0 = fc_b[0], l1 = fc_b[1];
#pragma unroll
    for (int g2 = 0; g2 < 8; ++g2) {
      l0 += s0[g2][tid];
      l1 += s1[g2][tid];
    }
    const int io = blockIdx.x * 32 + tid;
    float m = fmaxf(l0, l1);
    float lse = m + logf(expf(l0 - m) + expf(l1 - m));
    vf2 r = {l0 - lse, l1 - lse};
    *(vf2*)(out + (size_t)io * CC) = r;
  }
}

extern "C" void kernel_launch(void* const* d_in, const int* in_sizes, int n_in,
                              void* d_out, int out_size, void* d_ws, size_t ws_size,
                              hipStream_t stream) {
  const float* hsrc  = (const float*)d_in[0];  // (1,4096,64)
  const float* hadj  = (const float*)d_in[1];  // (2,1,4096,4096)
  const float* w     = (const float*)d_in[2];  // (2,4,64,64)
  const float* a_src = (const float*)d_in[3];  // (2,4,64,1)
  const float* a_dst = (const float*)d_in[4];  // (2,4,64,1)
  const float* fc_w  = (const float*)d_in[5];  // (2,128)
  const float* fc_b  = (const float*)d_in[6];  // (2,)
  float* out = (float*)d_out;                  // (1,4000,2) fp32

  char* ws = (char*)d_ws;
  // planar KH*NN planes, 128 KB each
  float* Ap  = (float*)(ws + 0);
  float* A5p = (float*)(ws + 131072);
  float* Bp  = (float*)(ws + 262144);
  float* B5p = (float*)(ws + 393216);
  float* G0p = (float*)(ws + 524288);
  float* G1p = (float*)(ws + 655360);
  float* P   = (float*)(ws + 786432);  // K*JSPLIT*H*3*NU floats (~6.1 MB)

  dim3 g1(NN / 64, KK * HH);
  gat_phase1<<<g1, 256, 0, stream>>>(hsrc, w, a_src, a_dst, fc_w,
                                     Ap, A5p, Bp, B5p, G0p, G1p);
  dim3 g2(NU / 32, KK * JSPLIT);
  gat_phase2<<<g2, 256, 0, stream>>>(hadj, Ap, A5p, Bp, B5p, G0p, G1p, P);
  gat_phase3<<<NU / 32, 256, 0, stream>>>(P, fc_b, out);
}

// Round 6
// 213.875 us; speedup vs baseline: 1.0721x; 1.0387x over previous
//
#include <hip/hip_runtime.h>
#include <math.h>

constexpr int KK = 2;
constexpr int HH = 4;
constexpr int NN = 4096;
constexpr int DD = 64;
constexpr int OO = 64;
constexpr int NU = 4000;
constexpr int CC = 2;
constexpr int JSPLIT = 16;
constexpr int JCHUNK = NN / JSPLIT;  // 256
constexpr float LOG2E = 1.44269504088896340736f;

typedef float vf4 __attribute__((ext_vector_type(4)));
typedef float vf2 __attribute__((ext_vector_type(2)));

__device__ __forceinline__ float fexp2(float x) {
#if __has_builtin(__builtin_amdgcn_exp2f)
  return __builtin_amdgcn_exp2f(x);
#else
  return exp2f(x);
#endif
}
__device__ __forceinline__ float frcp(float x) {
#if __has_builtin(__builtin_amdgcn_rcpf)
  return __builtin_amdgcn_rcpf(x);
#else
  return 1.0f / x;
#endif
}
__device__ __forceinline__ float ftanh(float x) {
  float e = fexp2(x * (2.0f * LOG2E));
  return 1.0f - 2.0f * frcp(e + 1.0f);
}

// ---------------------------------------------------------------------------
// Phase 1: per (k,h): hp = h @ w (4096x64 @ 64x64); per node i (PAIRED layout,
// as in the best-measured R1 config):
//   srcAA[kh][i] = {2^src', 2^(0.2 src')}   (src' = (tanh(hp_i).a_src)*log2e)
//   bb5  [kh][j] = {2^dst', 2^(0.2 dst')}
//   gg   [kh][j] = {hp_j.fc_w0, hp_j.fc_w1}
// Factorized leaky-softmax: exp2(max(s,0.2s)) = max(A*B, A5*B5).
// grid (64, K*H), block 256. Thread = 4 rows x 4 o tile; LDS transpose epi.
// Epilogue val = tid>>6 (wave-uniform branch).
// ---------------------------------------------------------------------------
__global__ __launch_bounds__(256) void gat_phase1(
    const float* __restrict__ hsrc, const float* __restrict__ w,
    const float* __restrict__ a_src, const float* __restrict__ a_dst,
    const float* __restrict__ fc_w,
    float* __restrict__ srcAA, float* __restrict__ bb5,
    float* __restrict__ gg) {
  const int kh = blockIdx.y;  // 0..7
  const int k = kh >> 2;
  const int i0 = blockIdx.x * 64;
  const int tid = threadIdx.x;

  __shared__ float h_s[DD][68];
  __shared__ float w_s[DD][OO];
  __shared__ float part[4][64][17];  // [val][row][og], padded

  {
    const vf4* wp = (const vf4*)(w + (size_t)kh * DD * OO);
    vf4* ws4 = (vf4*)w_s;
    for (int t = tid; t < DD * OO / 4; t += 256) ws4[t] = wp[t];
  }
  for (int t = tid; t < 1024; t += 256) {
    const int row = t >> 4;
    const int f4 = (t & 15) * 4;
    vf4 v = *(const vf4*)(hsrc + (size_t)(i0 + row) * DD + f4);
    h_s[f4 + 0][row] = v.x;
    h_s[f4 + 1][row] = v.y;
    h_s[f4 + 2][row] = v.z;
    h_s[f4 + 3][row] = v.w;
  }
  __syncthreads();

  const int og = tid & 15;
  const int rg = tid >> 4;
  const int o0 = og * 4;
  const int r0 = rg * 4;

  float hp[4][4];
#pragma unroll
  for (int j = 0; j < 4; ++j)
#pragma unroll
    for (int u = 0; u < 4; ++u) hp[j][u] = 0.0f;

#pragma unroll 8
  for (int f = 0; f < DD; ++f) {
    vf4 hv = *(const vf4*)&h_s[f][r0];
    vf4 wv = *(const vf4*)&w_s[f][o0];
    hp[0][0] = fmaf(hv.x, wv.x, hp[0][0]);
    hp[0][1] = fmaf(hv.x, wv.y, hp[0][1]);
    hp[0][2] = fmaf(hv.x, wv.z, hp[0][2]);
    hp[0][3] = fmaf(hv.x, wv.w, hp[0][3]);
    hp[1][0] = fmaf(hv.y, wv.x, hp[1][0]);
    hp[1][1] = fmaf(hv.y, wv.y, hp[1][1]);
    hp[1][2] = fmaf(hv.y, wv.z, hp[1][2]);
    hp[1][3] = fmaf(hv.y, wv.w, hp[1][3]);
    hp[2][0] = fmaf(hv.z, wv.x, hp[2][0]);
    hp[2][1] = fmaf(hv.z, wv.y, hp[2][1]);
    hp[2][2] = fmaf(hv.z, wv.z, hp[2][2]);
    hp[2][3] = fmaf(hv.z, wv.w, hp[2][3]);
    hp[3][0] = fmaf(hv.w, wv.x, hp[3][0]);
    hp[3][1] = fmaf(hv.w, wv.y, hp[3][1]);
    hp[3][2] = fmaf(hv.w, wv.z, hp[3][2]);
    hp[3][3] = fmaf(hv.w, wv.w, hp[3][3]);
  }

  float as[4], ad[4], f0[4], f1[4];
#pragma unroll
  for (int u = 0; u < 4; ++u) {
    as[u] = a_src[kh * OO + o0 + u];
    ad[u] = a_dst[kh * OO + o0 + u];
    f0[u] = fc_w[0 * (KK * OO) + k * OO + o0 + u];
    f1[u] = fc_w[1 * (KK * OO) + k * OO + o0 + u];
  }

#pragma unroll
  for (int j = 0; j < 4; ++j) {
    float sp = 0.0f, dp = 0.0f, g0 = 0.0f, g1 = 0.0f;
#pragma unroll
    for (int u = 0; u < 4; ++u) {
      float v = hp[j][u];
      float t = ftanh(v);
      sp = fmaf(t, as[u], sp);
      dp = fmaf(t, ad[u], dp);
      g0 = fmaf(v, f0[u], g0);
      g1 = fmaf(v, f1[u], g1);
    }
    part[0][r0 + j][og] = sp;
    part[1][r0 + j][og] = dp;
    part[2][r0 + j][og] = g0;
    part[3][r0 + j][og] = g1;
  }
  __syncthreads();

  {  // wave = val plane (uniform branch), lane = row j2; sum 16 og-partials
    const int val = tid >> 6;
    const int j2 = tid & 63;
    const float* pr = &part[val][j2][0];
    vf4 s0 = *(const vf4*)(pr + 0);
    vf4 s1 = *(const vf4*)(pr + 4);
    vf4 s2 = *(const vf4*)(pr + 8);
    vf4 s3 = *(const vf4*)(pr + 12);
    vf4 t4 = s0 + s1 + s2 + s3;
    float sum = t4.x + t4.y + t4.z + t4.w;
    const size_t idx = (size_t)kh * NN + i0 + j2;
    if (val == 0) {
      float sp = sum * LOG2E;
      vf2 v = {fexp2(sp), fexp2(0.2f * sp)};
      *(vf2*)(srcAA + idx * 2) = v;
    } else if (val == 1) {
      float dp = sum * LOG2E;
      vf2 v = {fexp2(dp), fexp2(0.2f * dp)};
      *(vf2*)(bb5 + idx * 2) = v;
    } else {
      gg[idx * 2 + (val - 2)] = sum;
    }
  }
}

// ---------------------------------------------------------------------------
// Phase 2: R1-replication (best measured config). Partial softmax sums over
// a 256-j chunk, 16 rows per block. grid (NU/16, K*JSPLIT) = (250, 32),
// block 256 = 4 waves. Lane = (jsub<<4) | row.
// LDS: paired (B,B5) and (g0,g1) planes, 16 KB + 3 KB reduce.
// Per 16-j tile per wave: 1 dense global adj vf4 (4 tiles prefetched
// upfront, plain loads) + 16 broadcast ds_read_b128 + exp-free VALU:
//   e = max(A*B, A5*B5)  [== exp2(leaky(s)), exact identity]
//   pa = adj*e; l += pa; a_c += pa*g_c
// Reduction: butterfly xor 16,32 + LDS combine across 4 waves.
// ---------------------------------------------------------------------------
__global__ __launch_bounds__(256) void gat_phase2(
    const float* __restrict__ adj, const float* __restrict__ srcAA,
    const float* __restrict__ bb5, const float* __restrict__ gg,
    float* __restrict__ P) {
  const int k = blockIdx.y >> 4;
  const int chunk = blockIdx.y & 15;
  const int r0 = blockIdx.x * 16;
  const int tid = threadIdx.x;
  const int wave = tid >> 6;
  const int lane = tid & 63;
  const int row = lane & 15;
  const int jsub = lane >> 4;
  const int i = r0 + row;
  const int j0 = chunk * JCHUNK;

  __shared__ float lds_bb[HH][JCHUNK * 2];
  __shared__ float lds_gg[HH][JCHUNK * 2];

  // stage both pair-planes: 2 arrays x 4 h x 512 floats = 1024 vf4
#pragma unroll
  for (int step = 0; step < 4; ++step) {
    const int idx = step * 256 + tid;
    const int sel = idx >> 9;
    const int h = (idx >> 7) & 3;
    const int pos = (idx & 127) * 4;
    const float* src =
        (sel ? gg : bb5) + ((size_t)(k * HH + h) * NN + j0) * 2 + pos;
    vf4 v = *(const vf4*)src;
    if (sel)
      *(vf4*)&lds_gg[h][pos] = v;
    else
      *(vf4*)&lds_bb[h][pos] = v;
  }

  vf2 AA[4];
#pragma unroll
  for (int h = 0; h < 4; ++h)
    AA[h] = *(const vf2*)(srcAA + ((size_t)(k * HH + h) * NN + i) * 2);

  float l[4], a0[4], a1[4];
#pragma unroll
  for (int h = 0; h < 4; ++h) {
    l[h] = 0.0f;
    a0[h] = 0.0f;
    a1[h] = 0.0f;
  }

  __syncthreads();

  // 16 tiles of 16 j; wave handles t = wave + s*4, s=0..3, all prefetched.
  const float* arow =
      adj + (size_t)k * NN * NN + (size_t)i * NN + j0 + jsub * 4;
  vf4 aj[4];
#pragma unroll
  for (int q = 0; q < 4; ++q)
    aj[q] = *(const vf4*)(arow + (wave + q * 4) * 16);

#pragma unroll
  for (int s = 0; s < 4; ++s) {
    const int t = wave + s * 4;
    const vf4 av = aj[s];
    const int jl = (t * 16 + jsub * 4) * 2;
#pragma unroll
    for (int h = 0; h < 4; ++h) {
      vf4 b01 = *(const vf4*)&lds_bb[h][jl];
      vf4 b23 = *(const vf4*)&lds_bb[h][jl + 4];
      vf4 g01 = *(const vf4*)&lds_gg[h][jl];
      vf4 g23 = *(const vf4*)&lds_gg[h][jl + 4];
      vf2 bp[4] = {{b01.x, b01.y}, {b01.z, b01.w}, {b23.x, b23.y}, {b23.z, b23.w}};
      vf2 gp[4] = {{g01.x, g01.y}, {g01.z, g01.w}, {g23.x, g23.y}, {g23.z, g23.w}};
#pragma unroll
      for (int jj = 0; jj < 4; ++jj) {
        vf2 PP = AA[h] * bp[jj];           // v_pk_mul_f32: {A*B, A5*B5}
        float e = fmaxf(PP.x, PP.y);       // = exp2(leaky(s)), exact
        float pa = e * av[jj];
        l[h] += pa;
        a0[h] = fmaf(pa, gp[jj].x, a0[h]);
        a1[h] = fmaf(pa, gp[jj].y, a1[h]);
      }
    }
  }

  // butterfly over jsub (lane bits 4,5)
#pragma unroll
  for (int h = 0; h < 4; ++h) {
    l[h] += __shfl_xor(l[h], 16, 64);
    l[h] += __shfl_xor(l[h], 32, 64);
    a0[h] += __shfl_xor(a0[h], 16, 64);
    a0[h] += __shfl_xor(a0[h], 32, 64);
    a1[h] += __shfl_xor(a1[h], 16, 64);
    a1[h] += __shfl_xor(a1[h], 32, 64);
  }

  // cross-wave combine: sred[wave][v][row], v = h*3+c
  __shared__ float sred[4][12][16];
  if (lane < 16) {
#pragma unroll
    for (int h = 0; h < 4; ++h) {
      sred[wave][h * 3 + 0][row] = l[h];
      sred[wave][h * 3 + 1][row] = a0[h];
      sred[wave][h * 3 + 2][row] = a1[h];
    }
  }
  __syncthreads();
  if (tid < 192) {
    const int v = tid >> 4;  // 0..11 = h*3+c
    const int rr = tid & 15;
    float sum =
        sred[0][v][rr] + sred[1][v][rr] + sred[2][v][rr] + sred[3][v][rr];
    const int h = v / 3, c = v % 3;
    // P layout: [k][chunk][h][{l,a0,a1}][i]
    size_t base =
        ((((size_t)(k * JSPLIT + chunk) * HH + h) * 3 + c)) * NU + (r0 + rr);
    P[base] = sum;
  }
}

// ---------------------------------------------------------------------------
// Phase 3: combine chunk partials, divide, mean heads, sum kinds, +bias,
// log_softmax over C=2. g = tid>>5 (wave-half-uniform plane) -> 128B
// coalesced P reads; LDS combine across the 8 (k,h) groups.
// ---------------------------------------------------------------------------
__global__ __launch_bounds__(256) void gat_phase3(
    const float* __restrict__ P, const float* __restrict__ fc_b,
    float* __restrict__ out) {
  const int tid = threadIdx.x;
  const int il = tid & 31;
  const int g = tid >> 5;  // 0..7 = (k,h), uniform per 32-lane half
  const int i = blockIdx.x * 32 + il;  // 125*32 == NU exactly
  const int k = g >> 2, h = g & 3;

  float ls = 0.0f, a0 = 0.0f, a1 = 0.0f;
#pragma unroll
  for (int ch = 0; ch < JSPLIT; ++ch) {
    size_t b = (((size_t)(k * JSPLIT + ch) * HH + h) * 3) * NU + i;
    ls += P[b];
    a0 += P[b + NU];
    a1 += P[b + 2 * (size_t)NU];
  }
  float inv = 1.0f / ls;
  float p0 = 0.25f * a0 * inv;
  float p1 = 0.25f * a1 * inv;

  __shared__ float s0[8][33], s1[8][33];
  s0[g][il] = p0;
  s1[g][il] = p1;
  __syncthreads();

  if (tid < 32) {
    float l0 = fc_b[0], l1 = fc_b[1];
#pragma unroll
    for (int g2 = 0; g2 < 8; ++g2) {
      l0 += s0[g2][tid];
      l1 += s1[g2][tid];
    }
    const int io = blockIdx.x * 32 + tid;
    float m = fmaxf(l0, l1);
    float lse = m + logf(expf(l0 - m) + expf(l1 - m));
    vf2 r = {l0 - lse, l1 - lse};
    *(vf2*)(out + (size_t)io * CC) = r;
  }
}

extern "C" void kernel_launch(void* const* d_in, const int* in_sizes, int n_in,
                              void* d_out, int out_size, void* d_ws, size_t ws_size,
                              hipStream_t stream) {
  const float* hsrc  = (const float*)d_in[0];  // (1,4096,64)
  const float* hadj  = (const float*)d_in[1];  // (2,1,4096,4096)
  const float* w     = (const float*)d_in[2];  // (2,4,64,64)
  const float* a_src = (const float*)d_in[3];  // (2,4,64,1)
  const float* a_dst = (const float*)d_in[4];  // (2,4,64,1)
  const float* fc_w  = (const float*)d_in[5];  // (2,128)
  const float* fc_b  = (const float*)d_in[6];  // (2,)
  float* out = (float*)d_out;                  // (1,4000,2) fp32

  char* ws = (char*)d_ws;
  float* srcAA = (float*)(ws + 0);        // K*H*N float2  (256 KB)
  float* bb5   = (float*)(ws + 262144);   // K*H*N float2  (256 KB)
  float* gg    = (float*)(ws + 524288);   // K*H*N float2  (256 KB)
  float* P     = (float*)(ws + 786432);   // K*JSPLIT*H*3*NU floats (~6.1 MB)

  dim3 g1(NN / 64, KK * HH);
  gat_phase1<<<g1, 256, 0, stream>>>(hsrc, w, a_src, a_dst, fc_w,
                                     srcAA, bb5, gg);
  dim3 g2(NU / 16, KK * JSPLIT);
  gat_phase2<<<g2, 256, 0, stream>>>(hadj, srcAA, bb5, gg, P);
  gat_phase3<<<NU / 32, 256, 0, stream>>>(P, fc_b, out);
}